// Round 1
// baseline (393.846 us; speedup 1.0000x reference)
//
#include <hip/hip_runtime.h>
#include <hip/hip_bf16.h>
#include <math.h>

// Problem constants
#define BATCH 4
#define CCH   512
#define HH    28
#define WW    28
#define HEADS 16
#define KW    7
#define DH    32
#define NPIX  (BATCH*HH*WW)        // 3136
#define HWPIX (HH*WW)              // 784
#define EPS   1e-5f

// ---------------- transpose BCHW -> (B*HW, C) row-major -----------------
__global__ __launch_bounds__(256) void k_transpose_xh(const float* __restrict__ x,
                                                      float* __restrict__ xh) {
    __shared__ float tile[32][33];
    int b  = blockIdx.z;
    int c0 = blockIdx.y * 32;
    int p0 = blockIdx.x * 32;
    int tx = threadIdx.x;      // 0..31
    int ty = threadIdx.y;      // 0..7
    for (int i = ty; i < 32; i += 8) {
        int c = c0 + i, p = p0 + tx;
        tile[i][tx] = (p < HWPIX) ? x[((size_t)b*CCH + c)*HWPIX + p] : 0.f;
    }
    __syncthreads();
    for (int i = ty; i < 32; i += 8) {
        int p = p0 + i, c = c0 + tx;
        if (p < HWPIX) xh[((size_t)b*HWPIX + p)*CCH + c] = tile[tx][i];
    }
}

// ---------------- generic fp32 tiled GEMM: C[m,n] = sum_k A[m,k]*Bw[n,k] + bias[n] ----
// EPI: 0 = bias only, 1 = bias + exact GELU, 2 = bias + residual(res[m*N+n])
template<int N, int K, int EPI>
__global__ __launch_bounds__(256) void k_gemm(const float* __restrict__ A,
                                              const float* __restrict__ Bw,
                                              const float* __restrict__ bias,
                                              const float* __restrict__ res,
                                              float* __restrict__ C) {
    constexpr int BM = 64, BN = 64, BK = 16;
    __shared__ float As[BK][BM + 4];
    __shared__ float Bs[BK][BN + 4];
    int tid = threadIdx.x;
    int m0 = blockIdx.x * BM;
    int n0 = blockIdx.y * BN;
    int tm = (tid & 15) * 4;
    int tn = (tid >> 4) * 4;
    int lm  = tid >> 2;          // 0..63 row in tile
    int lk4 = (tid & 3) * 4;     // k offset within BK

    const float* Aptr = A  + (size_t)(m0 + lm) * K + lk4;
    const float* Bptr = Bw + (size_t)(n0 + lm) * K + lk4;

    float acc[4][4] = {};
    for (int k0 = 0; k0 < K; k0 += BK) {
        float4 av = *(const float4*)(Aptr + k0);
        float4 bv = *(const float4*)(Bptr + k0);
        __syncthreads();
        As[lk4+0][lm] = av.x; As[lk4+1][lm] = av.y;
        As[lk4+2][lm] = av.z; As[lk4+3][lm] = av.w;
        Bs[lk4+0][lm] = bv.x; Bs[lk4+1][lm] = bv.y;
        Bs[lk4+2][lm] = bv.z; Bs[lk4+3][lm] = bv.w;
        __syncthreads();
#pragma unroll
        for (int kk = 0; kk < BK; ++kk) {
            float4 a4 = *(const float4*)&As[kk][tm];
            float4 b4 = *(const float4*)&Bs[kk][tn];
            float a[4] = {a4.x, a4.y, a4.z, a4.w};
            float bb[4] = {b4.x, b4.y, b4.z, b4.w};
#pragma unroll
            for (int i2 = 0; i2 < 4; ++i2)
#pragma unroll
                for (int j2 = 0; j2 < 4; ++j2)
                    acc[i2][j2] = fmaf(a[i2], bb[j2], acc[i2][j2]);
        }
    }
#pragma unroll
    for (int i2 = 0; i2 < 4; ++i2) {
        int m = m0 + tm + i2;
        float4 r4;
        if (EPI == 2) r4 = *(const float4*)&res[(size_t)m * N + n0 + tn];
        float out[4];
#pragma unroll
        for (int j2 = 0; j2 < 4; ++j2) {
            int n = n0 + tn + j2;
            float v = acc[i2][j2] + bias[n];
            if (EPI == 1) v = 0.5f * v * (1.0f + erff(v * 0.70710678118654752f));
            if (EPI == 2) v += (&r4.x)[j2];
            out[j2] = v;
        }
        *(float4*)&C[(size_t)m * N + n0 + tn] = make_float4(out[0], out[1], out[2], out[3]);
    }
}

// ---------------- neighborhood attention: one wave per (pixel, head) ----------------
__global__ __launch_bounds__(256) void k_attn(const float* __restrict__ qkv,
                                              const float* __restrict__ rpb,
                                              float* __restrict__ out) {
    int wid  = threadIdx.x >> 6;
    int lane = threadIdx.x & 63;
    int task = blockIdx.x * 4 + wid;       // NPIX*HEADS tasks
    int h   = task & 15;
    int pix = task >> 4;                    // b*784 + i*28 + j
    int j   = pix % 28;
    int t2  = pix / 28;
    int i   = t2 % 28;
    int b   = t2 / 28;

    const float* qptr = qkv + (size_t)pix * 1536 + h * 32;
    float4 qv[8];
#pragma unroll
    for (int d4 = 0; d4 < 8; ++d4) qv[d4] = *(const float4*)(qptr + d4 * 4);

    int si = min(max(i - 3, 0), 21);
    int sj = min(max(j - 3, 0), 21);

    float logit = -1e30f;
    if (lane < 49) {
        int kr = lane / 7, kc = lane % 7;
        int ii = si + kr, jj = sj + kc;
        int mn = b * HWPIX + ii * 28 + jj;
        const float* kptr = qkv + (size_t)mn * 1536 + 512 + h * 32;
        float acc = 0.f;
#pragma unroll
        for (int d4 = 0; d4 < 8; ++d4) {
            float4 kv = *(const float4*)(kptr + d4 * 4);
            acc = fmaf(qv[d4].x, kv.x, acc);
            acc = fmaf(qv[d4].y, kv.y, acc);
            acc = fmaf(qv[d4].z, kv.z, acc);
            acc = fmaf(qv[d4].w, kv.w, acc);
        }
        float bias = rpb[h * 169 + (ii - i + 6) * 13 + (jj - j + 6)];
        logit = acc * 0.17677669529663687f + bias;   // DH^-0.5
    }
    // wave softmax over 64 lanes (lanes >=49 hold -1e30)
    float mx = logit;
#pragma unroll
    for (int o = 32; o >= 1; o >>= 1) mx = fmaxf(mx, __shfl_xor(mx, o));
    float e = (lane < 49) ? __expf(logit - mx) : 0.f;
    float s = e;
#pragma unroll
    for (int o = 32; o >= 1; o >>= 1) s += __shfl_xor(s, o);
    float p = e / s;

    // phase 2: lane d accumulates over its n-range
    int d = lane & 31;
    int nb = (lane < 32) ? 0 : 25;
    int ne = (lane < 32) ? 25 : 49;
    float oacc = 0.f;
    for (int n = nb; n < ne; ++n) {
        float pn = __shfl(p, n);
        int kr = n / 7, kc = n % 7;
        int mn = b * HWPIX + (si + kr) * 28 + (sj + kc);
        oacc = fmaf(pn, qkv[(size_t)mn * 1536 + 1024 + h * 32 + d], oacc);
    }
    float other = __shfl_down(oacc, 32);
    if (lane < 32) out[(size_t)pix * CCH + h * 32 + d] = oacc + other;
}

// ---------------- batchnorm stats, stage 1: partial sums over row chunks -------------
__global__ __launch_bounds__(256) void k_bn_stats1(const float* __restrict__ y,
                                                   float* __restrict__ part) {
    int mc = blockIdx.x;              // 0..7
    int cc = blockIdx.y;              // 0..7
    int l  = threadIdx.x & 63;
    int r  = threadIdx.x >> 6;        // 0..3
    int c  = cc * 64 + l;
    float s = 0.f, s2 = 0.f;
    int mEnd = (mc + 1) * 392;
    for (int m = mc * 392 + r; m < mEnd; m += 4) {
        float v = y[(size_t)m * CCH + c];
        s += v; s2 = fmaf(v, v, s2);
    }
    __shared__ float sh[2][4][64];
    sh[0][r][l] = s; sh[1][r][l] = s2;
    __syncthreads();
    if (r == 0) {
        s  = sh[0][0][l] + sh[0][1][l] + sh[0][2][l] + sh[0][3][l];
        s2 = sh[1][0][l] + sh[1][1][l] + sh[1][2][l] + sh[1][3][l];
        part[mc * CCH + c]        = s;
        part[4096 + mc * CCH + c] = s2;
    }
}

// ---------------- batchnorm stats, stage 2: finalize scale/shift ---------------------
__global__ __launch_bounds__(512) void k_bn_stats2(const float* __restrict__ part,
                                                   const float* __restrict__ g,
                                                   const float* __restrict__ be,
                                                   float* __restrict__ ss) {
    int c = threadIdx.x;
    float s = 0.f, s2 = 0.f;
#pragma unroll
    for (int mc = 0; mc < 8; ++mc) {
        s  += part[mc * CCH + c];
        s2 += part[4096 + mc * CCH + c];
    }
    float mean = s * (1.0f / NPIX);
    float var  = s2 * (1.0f / NPIX) - mean * mean;
    float rstd = rsqrtf(var + EPS);
    float scale = rstd * g[c];
    ss[c]       = scale;
    ss[CCH + c] = be[c] - mean * scale;
}

// ---------------- batchnorm apply (pixel-major, elementwise) -------------------------
__global__ __launch_bounds__(256) void k_bn_apply(const float* __restrict__ y,
                                                  const float* __restrict__ ss,
                                                  float* __restrict__ x1) {
    size_t idx = ((size_t)blockIdx.x * 256 + threadIdx.x) * 4;
    int c = (int)(idx & (CCH - 1));
    float4 v = *(const float4*)&y[idx];
    float4 sc = *(const float4*)&ss[c];
    float4 sh = *(const float4*)&ss[CCH + c];
    v.x = fmaf(v.x, sc.x, sh.x);
    v.y = fmaf(v.y, sc.y, sh.y);
    v.z = fmaf(v.z, sc.z, sh.z);
    v.w = fmaf(v.w, sc.w, sh.w);
    *(float4*)&x1[idx] = v;
}

// ---------------- batchnorm apply + transpose to BCHW output ------------------------
__global__ __launch_bounds__(256) void k_bn2_out(const float* __restrict__ y,
                                                 const float* __restrict__ ss,
                                                 float* __restrict__ out) {
    __shared__ float tile[32][33];
    int b  = blockIdx.z;
    int p0 = blockIdx.y * 32;
    int c0 = blockIdx.x * 32;
    int tx = threadIdx.x, ty = threadIdx.y;
    for (int i = ty; i < 32; i += 8) {
        int p = p0 + i, c = c0 + tx;
        float v = 0.f;
        if (p < HWPIX) v = fmaf(y[((size_t)b*HWPIX + p)*CCH + c], ss[c], ss[CCH + c]);
        tile[i][tx] = v;
    }
    __syncthreads();
    for (int i = ty; i < 32; i += 8) {
        int c = c0 + i, p = p0 + tx;
        if (p < HWPIX) out[((size_t)b*CCH + c)*HWPIX + p] = tile[tx][i];
    }
}

// ---------------- host launch --------------------------------------------------------
extern "C" void kernel_launch(void* const* d_in, const int* in_sizes, int n_in,
                              void* d_out, int out_size, void* d_ws, size_t ws_size,
                              hipStream_t stream) {
    const float* x      = (const float*)d_in[0];
    const float* qkv_w  = (const float*)d_in[1];
    const float* qkv_b  = (const float*)d_in[2];
    const float* proj_w = (const float*)d_in[3];
    const float* proj_b = (const float*)d_in[4];
    const float* rpb    = (const float*)d_in[5];
    const float* w1     = (const float*)d_in[6];
    const float* b1     = (const float*)d_in[7];
    const float* w2     = (const float*)d_in[8];
    const float* b2     = (const float*)d_in[9];
    const float* g1     = (const float*)d_in[10];
    const float* be1    = (const float*)d_in[11];
    const float* g2     = (const float*)d_in[12];
    const float* be2    = (const float*)d_in[13];
    float* out = (float*)d_out;

    float* ws = (float*)d_ws;
    float* XH  = ws;                       // 3136x512
    float* QKV = ws + 1605632;             // 3136x1536
    float* ATT = ws + 6422528;             // 3136x512
    float* Y1  = ws + 8028160;             // 3136x512
    float* X1  = ws + 9633792;             // 3136x512
    float* T   = ws + 1605632;             // 3136x1024 (reuses QKV region, dead)
    float* Y2  = ws + 4816896;             // 3136x512  (reuses QKV region tail)
    float* PART= ws + 11239424;            // 8192
    float* SS  = ws + 11247616;            // 1024

    // 1) x (BCHW) -> XH (pixel-major)
    k_transpose_xh<<<dim3(25,16,BATCH), dim3(32,8), 0, stream>>>(x, XH);
    // 2) QKV = XH @ qkv_w^T + qkv_b
    k_gemm<1536,512,0><<<dim3(49,24), 256, 0, stream>>>(XH, qkv_w, qkv_b, nullptr, QKV);
    // 3) neighborhood attention
    k_attn<<<NPIX*HEADS/4, 256, 0, stream>>>(QKV, rpb, ATT);
    // 4) Y1 = ATT @ proj_w^T + proj_b + XH  (residual)
    k_gemm<512,512,2><<<dim3(49,8), 256, 0, stream>>>(ATT, proj_w, proj_b, XH, Y1);
    // 5) BN1 -> X1
    k_bn_stats1<<<dim3(8,8), 256, 0, stream>>>(Y1, PART);
    k_bn_stats2<<<1, 512, 0, stream>>>(PART, g1, be1, SS);
    k_bn_apply<<<NPIX*CCH/4/256, 256, 0, stream>>>(Y1, SS, X1);
    // 6) T = gelu(X1 @ w1^T + b1)
    k_gemm<1024,512,1><<<dim3(49,16), 256, 0, stream>>>(X1, w1, b1, nullptr, T);
    // 7) Y2 = T @ w2^T + b2 + X1
    k_gemm<512,1024,2><<<dim3(49,8), 256, 0, stream>>>(T, w2, b2, X1, Y2);
    // 8) BN2 -> out (BCHW)
    k_bn_stats1<<<dim3(8,8), 256, 0, stream>>>(Y2, PART);
    k_bn_stats2<<<1, 512, 0, stream>>>(PART, g2, be2, SS);
    k_bn2_out<<<dim3(16,25,BATCH), dim3(32,8), 0, stream>>>(Y2, SS, out);
}

// Round 2
// 204.843 us; speedup vs baseline: 1.9227x; 1.9227x over previous
//
#include <hip/hip_runtime.h>
#include <hip/hip_bf16.h>
#include <math.h>

#define BATCH 4
#define CCH   512
#define HWPIX 784
#define NPIX  3136
#define MPAD  3200
#define EPS   1e-5f

using f32x4  = __attribute__((ext_vector_type(4))) float;
using bf16x8 = __attribute__((ext_vector_type(8))) __bf16;

__device__ __forceinline__ short f2b(float f) {
    unsigned u = __float_as_uint(f);
    unsigned r = (u + 0x7FFFu + ((u >> 16) & 1u)) >> 16;   // RNE
    return (short)r;
}

__device__ __forceinline__ void gload_lds16(const void* g, void* l) {
    __builtin_amdgcn_global_load_lds((const __attribute__((address_space(1))) void*)g,
                                     (__attribute__((address_space(3))) void*)l, 16, 0, 0);
}

// ---------------- weights fp32 -> bf16 ----------------
__global__ __launch_bounds__(256) void k_f2b4(const float* __restrict__ in,
                                              short* __restrict__ out) {
    int i = (blockIdx.x * 256 + threadIdx.x) * 4;
    float4 v = *(const float4*)&in[i];
    unsigned a = (unsigned short)f2b(v.x) | ((unsigned)(unsigned short)f2b(v.y) << 16);
    unsigned b = (unsigned short)f2b(v.z) | ((unsigned)(unsigned short)f2b(v.w) << 16);
    *(uint2*)&out[i] = make_uint2(a, b);
}

// ---------------- transpose BCHW -> (B*HW, C), fp32 + bf16 ----------------
__global__ __launch_bounds__(256) void k_transpose_xh(const float* __restrict__ x,
                                                      float* __restrict__ xh,
                                                      short* __restrict__ xhb) {
    __shared__ float tile[32][33];
    int b  = blockIdx.z;
    int c0 = blockIdx.y * 32;
    int p0 = blockIdx.x * 32;
    int tx = threadIdx.x, ty = threadIdx.y;
    for (int i = ty; i < 32; i += 8) {
        int c = c0 + i, p = p0 + tx;
        tile[i][tx] = (p < HWPIX) ? x[((size_t)b * CCH + c) * HWPIX + p] : 0.f;
    }
    __syncthreads();
    for (int i = ty; i < 32; i += 8) {
        int p = p0 + i, c = c0 + tx;
        if (p < HWPIX) {
            size_t off = ((size_t)b * HWPIX + p) * CCH + c;
            float v = tile[tx][i];
            xh[off]  = v;
            xhb[off] = f2b(v);
        }
    }
}

// ---------------- bf16 MFMA GEMM: C = A @ Bw^T + bias (+epi) ----------------
// A: MPADxK bf16 row-major. Bw: NxK bf16 row-major. EPI: 0=bias,1=+gelu,2=+res
// OUTF: write fp32 Cf. OUTB: write bf16 Cb.
template<int BM, int BN, int N, int K, int EPI, int OUTF, int OUTB>
__global__ __launch_bounds__(256) void k_gemm_mfma(
        const short* __restrict__ A, const short* __restrict__ Bw,
        const float* __restrict__ bias, const float* __restrict__ res,
        float* __restrict__ Cf, short* __restrict__ Cb) {
    constexpr int BK = 64;
    constexpr int MR = BM / 32, NR = BN / 32;
    constexpr int AISS = BM / 32, BISS = BN / 32;
    __shared__ __align__(16) short As[BM * BK];
    __shared__ __align__(16) short Bs[BN * BK];
    const int tid  = threadIdx.x;
    const int wid  = tid >> 6, lane = tid & 63;
    const int wr   = wid >> 1, wc = wid & 1;            // 2x2 wave grid
    const int m0   = blockIdx.x * BM, n0 = blockIdx.y * BN;
    const int srow = tid >> 3, skc = tid & 7;           // staging map
    const int frow = lane & 15, fk = (lane >> 4) * 8;   // fragment map

    f32x4 acc[MR][NR];
    const f32x4 vzero = {0.f, 0.f, 0.f, 0.f};
#pragma unroll
    for (int m = 0; m < MR; ++m)
#pragma unroll
        for (int n = 0; n < NR; ++n) acc[m][n] = vzero;

    const short* Ab = A  + (size_t)(m0 + srow) * K + skc * 8;
    const short* Bb = Bw + (size_t)(n0 + srow) * K + skc * 8;

    for (int k0 = 0; k0 < K; k0 += BK) {
#pragma unroll
        for (int it = 0; it < AISS; ++it)
            gload_lds16(Ab + (size_t)it * 32 * K + k0, &As[(it * 256 + wid * 64) * 8]);
#pragma unroll
        for (int it = 0; it < BISS; ++it)
            gload_lds16(Bb + (size_t)it * 32 * K + k0, &Bs[(it * 256 + wid * 64) * 8]);
        __syncthreads();
#pragma unroll
        for (int kk = 0; kk < 2; ++kk) {
            bf16x8 af[MR], bfr[NR];
#pragma unroll
            for (int m = 0; m < MR; ++m)
                af[m] = *(const bf16x8*)&As[(wr * (BM / 2) + m * 16 + frow) * BK + kk * 32 + fk];
#pragma unroll
            for (int n = 0; n < NR; ++n)
                bfr[n] = *(const bf16x8*)&Bs[(wc * (BN / 2) + n * 16 + frow) * BK + kk * 32 + fk];
#pragma unroll
            for (int m = 0; m < MR; ++m)
#pragma unroll
                for (int n = 0; n < NR; ++n)
                    acc[m][n] = __builtin_amdgcn_mfma_f32_16x16x32_bf16(af[m], bfr[n], acc[m][n], 0, 0, 0);
        }
        __syncthreads();
    }
    const int crow0 = m0 + wr * (BM / 2) + (lane >> 4) * 4;
    const int ccol0 = n0 + wc * (BN / 2) + (lane & 15);
#pragma unroll
    for (int m = 0; m < MR; ++m) {
#pragma unroll
        for (int n = 0; n < NR; ++n) {
            const int col = ccol0 + n * 16;
            const float bv = bias[col];
#pragma unroll
            for (int j = 0; j < 4; ++j) {
                const int row = crow0 + m * 16 + j;
                float v = acc[m][n][j] + bv;
                if (EPI == 1) v = 0.5f * v * (1.0f + erff(v * 0.70710678118654752f));
                if (EPI == 2) v += res[(size_t)row * N + col];
                if (OUTF) Cf[(size_t)row * N + col] = v;
                if (OUTB) Cb[(size_t)row * N + col] = f2b(v);
            }
        }
    }
}

// ---------------- neighborhood attention: one wave per (pixel, head) ----------------
__global__ __launch_bounds__(256) void k_attn(const float* __restrict__ qkv,
                                              const float* __restrict__ rpb,
                                              short* __restrict__ outb) {
    __shared__ float qsh[4][32];
    __shared__ float psh[4][64];
    const int wid = threadIdx.x >> 6, lane = threadIdx.x & 63;
    const int task = blockIdx.x * 4 + wid;
    const int h = task & 15;
    const unsigned pix = (unsigned)task >> 4;
    const int j = pix % 28u;
    const unsigned t2 = pix / 28u;
    const int i = t2 % 28u;
    const int b = t2 / 28u;

    const float* qptr = qkv + (size_t)pix * 1536 + h * 32;
    if (lane < 8) *(float4*)&qsh[wid][lane * 4] = *(const float4*)(qptr + lane * 4);

    const int si = min(max(i - 3, 0), 21);
    const int sj = min(max(j - 3, 0), 21);
    const int kvbase = b * HWPIX;

    float e = 0.f, logit = -1e30f;
    if (lane < 49) {
        unsigned kr = (unsigned)lane / 7u, kc = (unsigned)lane % 7u;
        int ii = si + (int)kr, jj = sj + (int)kc;
        const float* kptr = qkv + (size_t)(kvbase + ii * 28 + jj) * 1536 + 512 + h * 32;
        float acc = 0.f;
#pragma unroll
        for (int d4 = 0; d4 < 8; ++d4) {
            float4 kv = *(const float4*)(kptr + d4 * 4);
            float4 qv = *(const float4*)&qsh[wid][d4 * 4];
            acc = fmaf(qv.x, kv.x, acc); acc = fmaf(qv.y, kv.y, acc);
            acc = fmaf(qv.z, kv.z, acc); acc = fmaf(qv.w, kv.w, acc);
        }
        logit = fmaf(acc, 0.17677669529663687f,
                     rpb[h * 169 + (ii - i + 6) * 13 + (jj - j + 6)]);
    }
    float mx = logit;
#pragma unroll
    for (int o = 32; o >= 1; o >>= 1) mx = fmaxf(mx, __shfl_xor(mx, o));
    if (lane < 49) e = __expf(logit - mx);
    float s = e;
#pragma unroll
    for (int o = 32; o >= 1; o >>= 1) s += __shfl_xor(s, o);
    psh[wid][lane] = e / s;

    const int d4 = lane & 7, ng = lane >> 3;
    float4 o4 = {0.f, 0.f, 0.f, 0.f};
    for (int n = ng; n < 49; n += 8) {
        unsigned kr = (unsigned)n / 7u, kc = (unsigned)n % 7u;
        const float* vptr = qkv + (size_t)(kvbase + (si + (int)kr) * 28 + sj + (int)kc) * 1536
                            + 1024 + h * 32 + d4 * 4;
        float pn = psh[wid][n];
        float4 vv = *(const float4*)vptr;
        o4.x = fmaf(pn, vv.x, o4.x); o4.y = fmaf(pn, vv.y, o4.y);
        o4.z = fmaf(pn, vv.z, o4.z); o4.w = fmaf(pn, vv.w, o4.w);
    }
#pragma unroll
    for (int off = 8; off <= 32; off <<= 1) {
        o4.x += __shfl_xor(o4.x, off); o4.y += __shfl_xor(o4.y, off);
        o4.z += __shfl_xor(o4.z, off); o4.w += __shfl_xor(o4.w, off);
    }
    if (ng == 0) {
        unsigned a  = (unsigned short)f2b(o4.x) | ((unsigned)(unsigned short)f2b(o4.y) << 16);
        unsigned b2 = (unsigned short)f2b(o4.z) | ((unsigned)(unsigned short)f2b(o4.w) << 16);
        *(uint2*)&outb[(size_t)pix * 512 + h * 32 + d4 * 4] = make_uint2(a, b2);
    }
}

// ---------------- batchnorm stats ----------------
__global__ __launch_bounds__(256) void k_bn_stats1(const float* __restrict__ y,
                                                   float* __restrict__ part) {
    int mc = blockIdx.x, cc = blockIdx.y;
    int l = threadIdx.x & 63, r = threadIdx.x >> 6;
    int c = cc * 64 + l;
    float s = 0.f, s2 = 0.f;
    int mEnd = (mc + 1) * 392;
    for (int m = mc * 392 + r; m < mEnd; m += 4) {
        float v = y[(size_t)m * CCH + c];
        s += v; s2 = fmaf(v, v, s2);
    }
    __shared__ float sh[2][4][64];
    sh[0][r][l] = s; sh[1][r][l] = s2;
    __syncthreads();
    if (r == 0) {
        s  = sh[0][0][l] + sh[0][1][l] + sh[0][2][l] + sh[0][3][l];
        s2 = sh[1][0][l] + sh[1][1][l] + sh[1][2][l] + sh[1][3][l];
        part[mc * CCH + c]        = s;
        part[4096 + mc * CCH + c] = s2;
    }
}

__global__ __launch_bounds__(512) void k_bn_stats2(const float* __restrict__ part,
                                                   const float* __restrict__ g,
                                                   const float* __restrict__ be,
                                                   float* __restrict__ ss) {
    int c = threadIdx.x;
    float s = 0.f, s2 = 0.f;
#pragma unroll
    for (int mc = 0; mc < 8; ++mc) {
        s  += part[mc * CCH + c];
        s2 += part[4096 + mc * CCH + c];
    }
    float mean = s * (1.0f / NPIX);
    float var  = s2 * (1.0f / NPIX) - mean * mean;
    float rstd = rsqrtf(var + EPS);
    float scale = rstd * g[c];
    ss[c]       = scale;
    ss[CCH + c] = be[c] - mean * scale;
}

// BN apply -> fp32 + bf16
__global__ __launch_bounds__(256) void k_bn_apply(const float* __restrict__ y,
                                                  const float* __restrict__ ss,
                                                  float* __restrict__ x1,
                                                  short* __restrict__ x1b) {
    size_t idx = ((size_t)blockIdx.x * 256 + threadIdx.x) * 4;
    int c = (int)(idx & (CCH - 1));
    float4 v  = *(const float4*)&y[idx];
    float4 sc = *(const float4*)&ss[c];
    float4 sh = *(const float4*)&ss[CCH + c];
    v.x = fmaf(v.x, sc.x, sh.x); v.y = fmaf(v.y, sc.y, sh.y);
    v.z = fmaf(v.z, sc.z, sh.z); v.w = fmaf(v.w, sc.w, sh.w);
    *(float4*)&x1[idx] = v;
    unsigned a = (unsigned short)f2b(v.x) | ((unsigned)(unsigned short)f2b(v.y) << 16);
    unsigned b = (unsigned short)f2b(v.z) | ((unsigned)(unsigned short)f2b(v.w) << 16);
    *(uint2*)&x1b[idx] = make_uint2(a, b);
}

// BN apply + transpose to BCHW output
__global__ __launch_bounds__(256) void k_bn2_out(const float* __restrict__ y,
                                                 const float* __restrict__ ss,
                                                 float* __restrict__ out) {
    __shared__ float tile[32][33];
    int b  = blockIdx.z;
    int p0 = blockIdx.y * 32;
    int c0 = blockIdx.x * 32;
    int tx = threadIdx.x, ty = threadIdx.y;
    for (int i = ty; i < 32; i += 8) {
        int p = p0 + i, c = c0 + tx;
        float v = 0.f;
        if (p < HWPIX) v = fmaf(y[((size_t)b * HWPIX + p) * CCH + c], ss[c], ss[CCH + c]);
        tile[i][tx] = v;
    }
    __syncthreads();
    for (int i = ty; i < 32; i += 8) {
        int c = c0 + i, p = p0 + tx;
        if (p < HWPIX) out[((size_t)b * CCH + c) * HWPIX + p] = tile[tx][i];
    }
}

// ---------------- host launch ----------------
extern "C" void kernel_launch(void* const* d_in, const int* in_sizes, int n_in,
                              void* d_out, int out_size, void* d_ws, size_t ws_size,
                              hipStream_t stream) {
    const float* x      = (const float*)d_in[0];
    const float* qkv_w  = (const float*)d_in[1];
    const float* qkv_b  = (const float*)d_in[2];
    const float* proj_w = (const float*)d_in[3];
    const float* proj_b = (const float*)d_in[4];
    const float* rpb    = (const float*)d_in[5];
    const float* w1     = (const float*)d_in[6];
    const float* b1     = (const float*)d_in[7];
    const float* w2     = (const float*)d_in[8];
    const float* b2     = (const float*)d_in[9];
    const float* g1     = (const float*)d_in[10];
    const float* be1    = (const float*)d_in[11];
    const float* g2     = (const float*)d_in[12];
    const float* be2    = (const float*)d_in[13];
    float* out = (float*)d_out;

    float* ws    = (float*)d_ws;
    float* XH    = ws;                          // MPADx512 f32 (later X1)
    short* XHb   = (short*)(ws + 1638400);      // MPADx512 bf16 (later X1b)
    float* QKV   = ws + 2457600;                // MPADx1536 f32
    short* Tb    = (short*)(ws + 2457600);      // MPADx1024 bf16 (reuses QKV)
    float* Y2    = ws + 4096000;                // MPADx512 f32 (reuses QKV tail)
    short* ATTb  = (short*)(ws + 7372800);      // MPADx512 bf16
    float* Y1    = ws + 8192000;                // MPADx512 f32
    short* Wqkv  = (short*)(ws + 9830400);
    short* Wproj = Wqkv + 786432;
    short* W1b   = Wproj + 262144;
    short* W2b   = W1b + 524288;
    float* PART  = ws + 10878976;
    float* SS    = ws + 10887168;

    k_f2b4<<<768, 256, 0, stream>>>(qkv_w, Wqkv);
    k_f2b4<<<256, 256, 0, stream>>>(proj_w, Wproj);
    k_f2b4<<<512, 256, 0, stream>>>(w1, W1b);
    k_f2b4<<<512, 256, 0, stream>>>(w2, W2b);
    k_transpose_xh<<<dim3(25, 16, BATCH), dim3(32, 8), 0, stream>>>(x, XH, XHb);
    k_gemm_mfma<128, 128, 1536, 512, 0, 1, 0>
        <<<dim3(25, 12), 256, 0, stream>>>(XHb, Wqkv, qkv_b, nullptr, QKV, nullptr);
    k_attn<<<12544, 256, 0, stream>>>(QKV, rpb, ATTb);
    k_gemm_mfma<64, 128, 512, 512, 2, 1, 0>
        <<<dim3(50, 4), 256, 0, stream>>>(ATTb, Wproj, proj_b, XH, Y1, nullptr);
    k_bn_stats1<<<dim3(8, 8), 256, 0, stream>>>(Y1, PART);
    k_bn_stats2<<<1, 512, 0, stream>>>(PART, g1, be1, SS);
    k_bn_apply<<<1568, 256, 0, stream>>>(Y1, SS, XH, XHb);
    k_gemm_mfma<128, 128, 1024, 512, 1, 0, 1>
        <<<dim3(25, 8), 256, 0, stream>>>(XHb, W1b, b1, nullptr, nullptr, Tb);
    k_gemm_mfma<64, 128, 512, 1024, 2, 1, 0>
        <<<dim3(50, 4), 256, 0, stream>>>(Tb, W2b, b2, XH, Y2, nullptr);
    k_bn_stats1<<<dim3(8, 8), 256, 0, stream>>>(Y2, PART);
    k_bn_stats2<<<1, 512, 0, stream>>>(PART, g2, be2, SS);
    k_bn2_out<<<dim3(16, 25, BATCH), dim3(32, 8), 0, stream>>>(Y2, SS, out);
}

// Round 3
// 183.596 us; speedup vs baseline: 2.1452x; 1.1157x over previous
//
#include <hip/hip_runtime.h>
#include <hip/hip_bf16.h>
#include <math.h>

#define BATCH 4
#define CCH   512
#define HWPIX 784
#define NPIX  3136
#define MPAD  3200
#define EPS   1e-5f

using f32x4  = __attribute__((ext_vector_type(4))) float;
using bf16x8 = __attribute__((ext_vector_type(8))) __bf16;

__device__ __forceinline__ short f2b(float f) {
    unsigned u = __float_as_uint(f);
    unsigned r = (u + 0x7FFFu + ((u >> 16) & 1u)) >> 16;   // RNE
    return (short)r;
}

__device__ __forceinline__ void gload_lds16(const void* g, void* l) {
    __builtin_amdgcn_global_load_lds((const __attribute__((address_space(1))) void*)g,
                                     (__attribute__((address_space(3))) void*)l, 16, 0, 0);
}

// dot of 8 bf16 (packed in uint4) against q[8], fp32 accum
__device__ __forceinline__ float bdot8(uint4 u, const float q[8], float acc) {
    acc = fmaf(q[0], __uint_as_float(u.x << 16),          acc);
    acc = fmaf(q[1], __uint_as_float(u.x & 0xffff0000u),  acc);
    acc = fmaf(q[2], __uint_as_float(u.y << 16),          acc);
    acc = fmaf(q[3], __uint_as_float(u.y & 0xffff0000u),  acc);
    acc = fmaf(q[4], __uint_as_float(u.z << 16),          acc);
    acc = fmaf(q[5], __uint_as_float(u.z & 0xffff0000u),  acc);
    acc = fmaf(q[6], __uint_as_float(u.w << 16),          acc);
    acc = fmaf(q[7], __uint_as_float(u.w & 0xffff0000u),  acc);
    return acc;
}

__device__ __forceinline__ void baxpy8(uint4 u, float e, float o[8]) {
    o[0] = fmaf(e, __uint_as_float(u.x << 16),          o[0]);
    o[1] = fmaf(e, __uint_as_float(u.x & 0xffff0000u),  o[1]);
    o[2] = fmaf(e, __uint_as_float(u.y << 16),          o[2]);
    o[3] = fmaf(e, __uint_as_float(u.y & 0xffff0000u),  o[3]);
    o[4] = fmaf(e, __uint_as_float(u.z << 16),          o[4]);
    o[5] = fmaf(e, __uint_as_float(u.z & 0xffff0000u),  o[5]);
    o[6] = fmaf(e, __uint_as_float(u.w << 16),          o[6]);
    o[7] = fmaf(e, __uint_as_float(u.w & 0xffff0000u),  o[7]);
}

// ---------------- weights fp32 -> bf16 ----------------
__global__ __launch_bounds__(256) void k_f2b4(const float* __restrict__ in,
                                              short* __restrict__ out) {
    int i = (blockIdx.x * 256 + threadIdx.x) * 4;
    float4 v = *(const float4*)&in[i];
    unsigned a = (unsigned short)f2b(v.x) | ((unsigned)(unsigned short)f2b(v.y) << 16);
    unsigned b = (unsigned short)f2b(v.z) | ((unsigned)(unsigned short)f2b(v.w) << 16);
    *(uint2*)&out[i] = make_uint2(a, b);
}

// ---------------- transpose BCHW -> (B*HW, C), fp32 + bf16 ----------------
__global__ __launch_bounds__(256) void k_transpose_xh(const float* __restrict__ x,
                                                      float* __restrict__ xh,
                                                      short* __restrict__ xhb) {
    __shared__ float tile[32][33];
    int b  = blockIdx.z;
    int c0 = blockIdx.y * 32;
    int p0 = blockIdx.x * 32;
    int tx = threadIdx.x, ty = threadIdx.y;
    for (int i = ty; i < 32; i += 8) {
        int c = c0 + i, p = p0 + tx;
        tile[i][tx] = (p < HWPIX) ? x[((size_t)b * CCH + c) * HWPIX + p] : 0.f;
    }
    __syncthreads();
    for (int i = ty; i < 32; i += 8) {
        int p = p0 + i, c = c0 + tx;
        if (p < HWPIX) {
            size_t off = ((size_t)b * HWPIX + p) * CCH + c;
            float v = tile[tx][i];
            xh[off]  = v;
            xhb[off] = f2b(v);
        }
    }
}

// ---------------- bf16 MFMA GEMM: C = A @ Bw^T + bias (+epi) ----------------
template<int BM, int BN, int N, int K, int EPI, int OUTF, int OUTB>
__global__ __launch_bounds__(256) void k_gemm_mfma(
        const short* __restrict__ A, const short* __restrict__ Bw,
        const float* __restrict__ bias, const float* __restrict__ res,
        float* __restrict__ Cf, short* __restrict__ Cb) {
    constexpr int BK = 64;
    constexpr int MR = BM / 32, NR = BN / 32;
    constexpr int AISS = BM / 32, BISS = BN / 32;
    __shared__ __align__(16) short As[BM * BK];
    __shared__ __align__(16) short Bs[BN * BK];
    const int tid  = threadIdx.x;
    const int wid  = tid >> 6, lane = tid & 63;
    const int wr   = wid >> 1, wc = wid & 1;
    const int m0   = blockIdx.x * BM, n0 = blockIdx.y * BN;
    const int srow = tid >> 3, skc = tid & 7;
    const int frow = lane & 15, fk = (lane >> 4) * 8;

    f32x4 acc[MR][NR];
    const f32x4 vzero = {0.f, 0.f, 0.f, 0.f};
#pragma unroll
    for (int m = 0; m < MR; ++m)
#pragma unroll
        for (int n = 0; n < NR; ++n) acc[m][n] = vzero;

    const short* Ab = A  + (size_t)(m0 + srow) * K + skc * 8;
    const short* Bb = Bw + (size_t)(n0 + srow) * K + skc * 8;

    for (int k0 = 0; k0 < K; k0 += BK) {
#pragma unroll
        for (int it = 0; it < AISS; ++it)
            gload_lds16(Ab + (size_t)it * 32 * K + k0, &As[(it * 256 + wid * 64) * 8]);
#pragma unroll
        for (int it = 0; it < BISS; ++it)
            gload_lds16(Bb + (size_t)it * 32 * K + k0, &Bs[(it * 256 + wid * 64) * 8]);
        __syncthreads();
#pragma unroll
        for (int kk = 0; kk < 2; ++kk) {
            bf16x8 af[MR], bfr[NR];
#pragma unroll
            for (int m = 0; m < MR; ++m)
                af[m] = *(const bf16x8*)&As[(wr * (BM / 2) + m * 16 + frow) * BK + kk * 32 + fk];
#pragma unroll
            for (int n = 0; n < NR; ++n)
                bfr[n] = *(const bf16x8*)&Bs[(wc * (BN / 2) + n * 16 + frow) * BK + kk * 32 + fk];
#pragma unroll
            for (int m = 0; m < MR; ++m)
#pragma unroll
                for (int n = 0; n < NR; ++n)
                    acc[m][n] = __builtin_amdgcn_mfma_f32_16x16x32_bf16(af[m], bfr[n], acc[m][n], 0, 0, 0);
        }
        __syncthreads();
    }
    const int crow0 = m0 + wr * (BM / 2) + (lane >> 4) * 4;
    const int ccol0 = n0 + wc * (BN / 2) + (lane & 15);
#pragma unroll
    for (int m = 0; m < MR; ++m) {
#pragma unroll
        for (int n = 0; n < NR; ++n) {
            const int col = ccol0 + n * 16;
            const float bv = bias[col];
#pragma unroll
            for (int j = 0; j < 4; ++j) {
                const int row = crow0 + m * 16 + j;
                float v = acc[m][n][j] + bv;
                if (EPI == 1) v = 0.5f * v * (1.0f + erff(v * 0.70710678118654752f));
                if (EPI == 2) v += res[(size_t)row * N + col];
                if (OUTF) Cf[(size_t)row * N + col] = v;
                if (OUTB) Cb[(size_t)row * N + col] = f2b(v);
            }
        }
    }
}

// ---------------- neighborhood attention: one wave per pixel, all 16 heads ----------
// lane = h*4 + d2 ; lane owns channels [h*32 + d2*8, +8)
__global__ __launch_bounds__(256) void k_attn(const short* __restrict__ qkvb,
                                              const float* __restrict__ rpb,
                                              short* __restrict__ outb) {
    __shared__ float lsh[4][16][50];
    const int wid = threadIdx.x >> 6, lane = threadIdx.x & 63;
    const int pix = blockIdx.x * 4 + wid;
    const int h = lane >> 2, d2 = lane & 3;
    const unsigned upix = (unsigned)pix;
    const int j = upix % 28u;
    const unsigned t2 = upix / 28u;
    const int i = t2 % 28u;
    const int b = t2 / 28u;
    const int si = min(max(i - 3, 0), 21), sj = min(max(j - 3, 0), 21);
    const int oi = si - i + 6, oj = sj - j + 6;
    const int pbase = b * HWPIX + si * 28 + sj;

    // load q (8 bf16) -> f32, pre-scale
    float q[8];
    {
        uint4 qu = *(const uint4*)(qkvb + (size_t)pix * 1536 + lane * 8);
        const float sc = 0.17677669529663687f;
        q[0] = __uint_as_float(qu.x << 16) * sc;
        q[1] = __uint_as_float(qu.x & 0xffff0000u) * sc;
        q[2] = __uint_as_float(qu.y << 16) * sc;
        q[3] = __uint_as_float(qu.y & 0xffff0000u) * sc;
        q[4] = __uint_as_float(qu.z << 16) * sc;
        q[5] = __uint_as_float(qu.z & 0xffff0000u) * sc;
        q[6] = __uint_as_float(qu.w << 16) * sc;
        q[7] = __uint_as_float(qu.w & 0xffff0000u) * sc;
    }
    const short* kbase = qkvb + (size_t)pbase * 1536 + 512 + lane * 8;
    const float* rb = rpb + h * 169 + oi * 13 + oj;

    // pass 1: logits
    for (int kr = 0; kr < 7; ++kr) {
        const short* krow = kbase + kr * (28 * 1536);
        const float* brow = rb + kr * 13;
#pragma unroll
        for (int kc = 0; kc < 7; ++kc) {
            uint4 ku = *(const uint4*)(krow + kc * 1536);
            float dot = bdot8(ku, q, 0.f);
            dot += __shfl_xor(dot, 1);
            dot += __shfl_xor(dot, 2);
            if (d2 == 0) lsh[wid][h][kr * 7 + kc] = dot + brow[kc];
        }
    }
    __syncthreads();

    // pass 2: softmax (each lane owns n = d2, d2+4, ...)
    float mx = -1e30f;
    for (int n = d2; n < 49; n += 4) mx = fmaxf(mx, lsh[wid][h][n]);
    mx = fmaxf(mx, __shfl_xor(mx, 1));
    mx = fmaxf(mx, __shfl_xor(mx, 2));
    float s = 0.f;
    for (int n = d2; n < 49; n += 4) {
        float e = __expf(lsh[wid][h][n] - mx);
        lsh[wid][h][n] = e;
        s += e;
    }
    s += __shfl_xor(s, 1);
    s += __shfl_xor(s, 2);
    __syncthreads();

    // pass 3: PV
    const short* vbase = qkvb + (size_t)pbase * 1536 + 1024 + lane * 8;
    float o[8] = {0.f, 0.f, 0.f, 0.f, 0.f, 0.f, 0.f, 0.f};
    for (int kr = 0; kr < 7; ++kr) {
        const short* vrow = vbase + kr * (28 * 1536);
        const float* prow = &lsh[wid][h][kr * 7];
#pragma unroll
        for (int kc = 0; kc < 7; ++kc) {
            uint4 vu = *(const uint4*)(vrow + kc * 1536);
            baxpy8(vu, prow[kc], o);
        }
    }
    const float rs = 1.f / s;
    unsigned p0 = (unsigned short)f2b(o[0] * rs) | ((unsigned)(unsigned short)f2b(o[1] * rs) << 16);
    unsigned p1 = (unsigned short)f2b(o[2] * rs) | ((unsigned)(unsigned short)f2b(o[3] * rs) << 16);
    unsigned p2 = (unsigned short)f2b(o[4] * rs) | ((unsigned)(unsigned short)f2b(o[5] * rs) << 16);
    unsigned p3 = (unsigned short)f2b(o[6] * rs) | ((unsigned)(unsigned short)f2b(o[7] * rs) << 16);
    *(uint4*)&outb[(size_t)pix * 512 + lane * 8] = make_uint4(p0, p1, p2, p3);
}

// ---------------- batchnorm stats ----------------
__global__ __launch_bounds__(256) void k_bn_stats1(const float* __restrict__ y,
                                                   float* __restrict__ part) {
    int mc = blockIdx.x, cc = blockIdx.y;
    int l = threadIdx.x & 63, r = threadIdx.x >> 6;
    int c = cc * 64 + l;
    float s = 0.f, s2 = 0.f;
    int mEnd = (mc + 1) * 392;
    for (int m = mc * 392 + r; m < mEnd; m += 4) {
        float v = y[(size_t)m * CCH + c];
        s += v; s2 = fmaf(v, v, s2);
    }
    __shared__ float sh[2][4][64];
    sh[0][r][l] = s; sh[1][r][l] = s2;
    __syncthreads();
    if (r == 0) {
        s  = sh[0][0][l] + sh[0][1][l] + sh[0][2][l] + sh[0][3][l];
        s2 = sh[1][0][l] + sh[1][1][l] + sh[1][2][l] + sh[1][3][l];
        part[mc * CCH + c]        = s;
        part[4096 + mc * CCH + c] = s2;
    }
}

__global__ __launch_bounds__(512) void k_bn_stats2(const float* __restrict__ part,
                                                   const float* __restrict__ g,
                                                   const float* __restrict__ be,
                                                   float* __restrict__ ss) {
    int c = threadIdx.x;
    float s = 0.f, s2 = 0.f;
#pragma unroll
    for (int mc = 0; mc < 8; ++mc) {
        s  += part[mc * CCH + c];
        s2 += part[4096 + mc * CCH + c];
    }
    float mean = s * (1.0f / NPIX);
    float var  = s2 * (1.0f / NPIX) - mean * mean;
    float rstd = rsqrtf(var + EPS);
    float scale = rstd * g[c];
    ss[c]       = scale;
    ss[CCH + c] = be[c] - mean * scale;
}

__global__ __launch_bounds__(256) void k_bn_apply(const float* __restrict__ y,
                                                  const float* __restrict__ ss,
                                                  float* __restrict__ x1,
                                                  short* __restrict__ x1b) {
    size_t idx = ((size_t)blockIdx.x * 256 + threadIdx.x) * 4;
    int c = (int)(idx & (CCH - 1));
    float4 v  = *(const float4*)&y[idx];
    float4 sc = *(const float4*)&ss[c];
    float4 sh = *(const float4*)&ss[CCH + c];
    v.x = fmaf(v.x, sc.x, sh.x); v.y = fmaf(v.y, sc.y, sh.y);
    v.z = fmaf(v.z, sc.z, sh.z); v.w = fmaf(v.w, sc.w, sh.w);
    *(float4*)&x1[idx] = v;
    unsigned a = (unsigned short)f2b(v.x) | ((unsigned)(unsigned short)f2b(v.y) << 16);
    unsigned b = (unsigned short)f2b(v.z) | ((unsigned)(unsigned short)f2b(v.w) << 16);
    *(uint2*)&x1b[idx] = make_uint2(a, b);
}

__global__ __launch_bounds__(256) void k_bn2_out(const float* __restrict__ y,
                                                 const float* __restrict__ ss,
                                                 float* __restrict__ out) {
    __shared__ float tile[32][33];
    int b  = blockIdx.z;
    int p0 = blockIdx.y * 32;
    int c0 = blockIdx.x * 32;
    int tx = threadIdx.x, ty = threadIdx.y;
    for (int i = ty; i < 32; i += 8) {
        int p = p0 + i, c = c0 + tx;
        float v = 0.f;
        if (p < HWPIX) v = fmaf(y[((size_t)b * HWPIX + p) * CCH + c], ss[c], ss[CCH + c]);
        tile[i][tx] = v;
    }
    __syncthreads();
    for (int i = ty; i < 32; i += 8) {
        int c = c0 + i, p = p0 + tx;
        if (p < HWPIX) out[((size_t)b * CCH + c) * HWPIX + p] = tile[tx][i];
    }
}

// ---------------- host launch ----------------
extern "C" void kernel_launch(void* const* d_in, const int* in_sizes, int n_in,
                              void* d_out, int out_size, void* d_ws, size_t ws_size,
                              hipStream_t stream) {
    const float* x      = (const float*)d_in[0];
    const float* qkv_w  = (const float*)d_in[1];
    const float* qkv_b  = (const float*)d_in[2];
    const float* proj_w = (const float*)d_in[3];
    const float* proj_b = (const float*)d_in[4];
    const float* rpb    = (const float*)d_in[5];
    const float* w1     = (const float*)d_in[6];
    const float* b1     = (const float*)d_in[7];
    const float* w2     = (const float*)d_in[8];
    const float* b2     = (const float*)d_in[9];
    const float* g1     = (const float*)d_in[10];
    const float* be1    = (const float*)d_in[11];
    const float* g2     = (const float*)d_in[12];
    const float* be2    = (const float*)d_in[13];
    float* out = (float*)d_out;

    float* ws    = (float*)d_ws;
    float* XH    = ws;                          // MPADx512 f32 (becomes X1)
    short* XHb   = (short*)(ws + 1638400);      // MPADx512 bf16 (becomes X1b)
    short* QKVb  = (short*)(ws + 2457600);      // MPADx1536 bf16 (becomes Tb)
    short* Tb    = QKVb;                        // MPADx1024 bf16 (reuse, QKV dead)
    short* ATTb  = (short*)(ws + 4915200);      // MPADx512 bf16
    float* Y1    = ws + 5734400;                // MPADx512 f32 (becomes Y2)
    float* Y2    = Y1;
    short* Wqkv  = (short*)(ws + 7372800);      // 786432 bf16
    short* Wproj = Wqkv + 786432;               // 262144 bf16
    short* W1b   = Wproj + 262144;              // 524288 bf16
    short* W2b   = W1b + 524288;                // 524288 bf16
    float* PART  = ws + 8421376;
    float* SS    = ws + 8429568;

    k_f2b4<<<768, 256, 0, stream>>>(qkv_w, Wqkv);
    k_f2b4<<<256, 256, 0, stream>>>(proj_w, Wproj);
    k_f2b4<<<512, 256, 0, stream>>>(w1, W1b);
    k_f2b4<<<512, 256, 0, stream>>>(w2, W2b);
    k_transpose_xh<<<dim3(25, 16, BATCH), dim3(32, 8), 0, stream>>>(x, XH, XHb);
    k_gemm_mfma<128, 128, 1536, 512, 0, 0, 1>
        <<<dim3(25, 12), 256, 0, stream>>>(XHb, Wqkv, qkv_b, nullptr, nullptr, QKVb);
    k_attn<<<784, 256, 0, stream>>>(QKVb, rpb, ATTb);
    k_gemm_mfma<64, 128, 512, 512, 2, 1, 0>
        <<<dim3(50, 4), 256, 0, stream>>>(ATTb, Wproj, proj_b, XH, Y1, nullptr);
    k_bn_stats1<<<dim3(8, 8), 256, 0, stream>>>(Y1, PART);
    k_bn_stats2<<<1, 512, 0, stream>>>(PART, g1, be1, SS);
    k_bn_apply<<<1568, 256, 0, stream>>>(Y1, SS, XH, XHb);
    k_gemm_mfma<128, 128, 1024, 512, 1, 0, 1>
        <<<dim3(25, 8), 256, 0, stream>>>(XHb, W1b, b1, nullptr, nullptr, Tb);
    k_gemm_mfma<64, 128, 512, 1024, 2, 1, 0>
        <<<dim3(50, 4), 256, 0, stream>>>(Tb, W2b, b2, XH, Y2, nullptr);
    k_bn_stats1<<<dim3(8, 8), 256, 0, stream>>>(Y2, PART);
    k_bn_stats2<<<1, 512, 0, stream>>>(PART, g2, be2, SS);
    k_bn2_out<<<dim3(16, 25, BATCH), dim3(32, 8), 0, stream>>>(Y2, SS, out);
}

// Round 4
// 132.957 us; speedup vs baseline: 2.9622x; 1.3809x over previous
//
#include <hip/hip_runtime.h>
#include <hip/hip_bf16.h>
#include <math.h>

#define BATCH 4
#define CCH   512
#define HWPIX 784
#define NPIX  3136
#define MPAD  3200
#define EPS   1e-5f

using f32x4  = __attribute__((ext_vector_type(4))) float;
using bf16x8 = __attribute__((ext_vector_type(8))) __bf16;

__device__ __forceinline__ short f2b(float f) {
    unsigned u = __float_as_uint(f);
    unsigned r = (u + 0x7FFFu + ((u >> 16) & 1u)) >> 16;   // RNE
    return (short)r;
}

__device__ __forceinline__ void gload_lds16(const void* g, void* l) {
    __builtin_amdgcn_global_load_lds((const __attribute__((address_space(1))) void*)g,
                                     (__attribute__((address_space(3))) void*)l, 16, 0, 0);
}

// ---------------- all weights fp32 -> bf16, one launch ----------------
__global__ __launch_bounds__(256) void k_f2b_all(const float* __restrict__ s0,
                                                 const float* __restrict__ s1,
                                                 const float* __restrict__ s2,
                                                 const float* __restrict__ s3,
                                                 short* __restrict__ out) {
    int i = (blockIdx.x * 256 + threadIdx.x) * 4;
    const float* src; int base;
    if (i < 786432)       { src = s0; base = 0; }
    else if (i < 1048576) { src = s1; base = 786432; }
    else if (i < 1572864) { src = s2; base = 1048576; }
    else                  { src = s3; base = 1572864; }
    float4 v = *(const float4*)&src[i - base];
    unsigned a = (unsigned short)f2b(v.x) | ((unsigned)(unsigned short)f2b(v.y) << 16);
    unsigned b = (unsigned short)f2b(v.z) | ((unsigned)(unsigned short)f2b(v.w) << 16);
    *(uint2*)&out[i] = make_uint2(a, b);
}

// ---------------- transpose BCHW -> (B*HW, C), fp32 + bf16 ----------------
__global__ __launch_bounds__(256) void k_transpose_xh(const float* __restrict__ x,
                                                      float* __restrict__ xh,
                                                      short* __restrict__ xhb) {
    __shared__ float tile[32][33];
    int b  = blockIdx.z;
    int c0 = blockIdx.y * 32;
    int p0 = blockIdx.x * 32;
    int tx = threadIdx.x, ty = threadIdx.y;
    for (int i = ty; i < 32; i += 8) {
        int c = c0 + i, p = p0 + tx;
        tile[i][tx] = (p < HWPIX) ? x[((size_t)b * CCH + c) * HWPIX + p] : 0.f;
    }
    __syncthreads();
    for (int i = ty; i < 32; i += 8) {
        int p = p0 + i, c = c0 + tx;
        if (p < HWPIX) {
            size_t off = ((size_t)b * HWPIX + p) * CCH + c;
            float v = tile[tx][i];
            xh[off]  = v;
            xhb[off] = f2b(v);
        }
    }
}

// ---------------- bf16 MFMA GEMM: C = A @ Bw^T + bias (+epi) ----------------
// EPI: 0=bias, 1=+gelu, 2=+residual. STATS: accumulate per-block col partials.
template<int BM, int BN, int N, int K, int EPI, int OUTF, int OUTB, int STATS>
__global__ __launch_bounds__(256) void k_gemm_mfma(
        const short* __restrict__ A, const short* __restrict__ Bw,
        const float* __restrict__ bias, const float* __restrict__ res,
        float* __restrict__ Cf, short* __restrict__ Cb,
        float* __restrict__ part) {
    constexpr int BK = 64;
    constexpr int MR = BM / 32, NR = BN / 32;
    constexpr int AISS = BM / 32, BISS = BN / 32;
    __shared__ __align__(16) short As[BM * BK];
    __shared__ __align__(16) short Bs[BN * BK];
    const int tid  = threadIdx.x;
    const int wid  = tid >> 6, lane = tid & 63;
    const int wr   = wid >> 1, wc = wid & 1;
    const int m0   = blockIdx.x * BM, n0 = blockIdx.y * BN;
    const int srow = tid >> 3, skc = tid & 7;
    const int frow = lane & 15, fk = (lane >> 4) * 8;

    f32x4 acc[MR][NR];
    const f32x4 vzero = {0.f, 0.f, 0.f, 0.f};
#pragma unroll
    for (int m = 0; m < MR; ++m)
#pragma unroll
        for (int n = 0; n < NR; ++n) acc[m][n] = vzero;

    const short* Ab = A  + (size_t)(m0 + srow) * K + skc * 8;
    const short* Bb = Bw + (size_t)(n0 + srow) * K + skc * 8;

    for (int k0 = 0; k0 < K; k0 += BK) {
#pragma unroll
        for (int it = 0; it < AISS; ++it)
            gload_lds16(Ab + (size_t)it * 32 * K + k0, &As[(it * 256 + wid * 64) * 8]);
#pragma unroll
        for (int it = 0; it < BISS; ++it)
            gload_lds16(Bb + (size_t)it * 32 * K + k0, &Bs[(it * 256 + wid * 64) * 8]);
        __syncthreads();
#pragma unroll
        for (int kk = 0; kk < 2; ++kk) {
            bf16x8 af[MR], bfr[NR];
#pragma unroll
            for (int m = 0; m < MR; ++m)
                af[m] = *(const bf16x8*)&As[(wr * (BM / 2) + m * 16 + frow) * BK + kk * 32 + fk];
#pragma unroll
            for (int n = 0; n < NR; ++n)
                bfr[n] = *(const bf16x8*)&Bs[(wc * (BN / 2) + n * 16 + frow) * BK + kk * 32 + fk];
#pragma unroll
            for (int m = 0; m < MR; ++m)
#pragma unroll
                for (int n = 0; n < NR; ++n)
                    acc[m][n] = __builtin_amdgcn_mfma_f32_16x16x32_bf16(af[m], bfr[n], acc[m][n], 0, 0, 0);
        }
        __syncthreads();
    }
    const int crow0 = m0 + wr * (BM / 2) + (lane >> 4) * 4;
    const int ccol0 = n0 + wc * (BN / 2) + (lane & 15);
    float ls[NR], ls2[NR];
#pragma unroll
    for (int n = 0; n < NR; ++n) { ls[n] = 0.f; ls2[n] = 0.f; }
#pragma unroll
    for (int m = 0; m < MR; ++m) {
#pragma unroll
        for (int n = 0; n < NR; ++n) {
            const int col = ccol0 + n * 16;
            const float bv = bias[col];
#pragma unroll
            for (int j = 0; j < 4; ++j) {
                const int row = crow0 + m * 16 + j;
                float v = acc[m][n][j] + bv;
                if (EPI == 1) v = 0.5f * v * (1.0f + erff(v * 0.70710678118654752f));
                if (EPI == 2) v += res[(size_t)row * N + col];
                if (OUTF) Cf[(size_t)row * N + col] = v;
                if (OUTB) Cb[(size_t)row * N + col] = f2b(v);
                if (STATS && row < NPIX) { ls[n] += v; ls2[n] = fmaf(v, v, ls2[n]); }
            }
        }
    }
    if (STATS) {
        // reduce per-column partials across the 8 row-groups, write to part
        float* red  = (float*)As;            // [8][128]
        float* red2 = red + 8 * 128;         // [8][128]
        const int rrow = wr * 4 + (lane >> 4);
#pragma unroll
        for (int n = 0; n < NR; ++n) {
            int cslot = wc * (BN / 2) + n * 16 + (lane & 15);
            red [rrow * BN + cslot] = ls[n];
            red2[rrow * BN + cslot] = ls2[n];
        }
        __syncthreads();
        if (tid < BN) {
            float s = 0.f, s2 = 0.f;
#pragma unroll
            for (int r = 0; r < 8; ++r) { s += red[r * BN + tid]; s2 += red2[r * BN + tid]; }
            part[blockIdx.x * N + n0 + tid]               = s;
            part[50 * N + blockIdx.x * N + n0 + tid]      = s2;
        }
    }
}

// ---------------- neighborhood attention: one wave per (pixel, head-group of 8) -----
// lane = h3*8 + d3 ; lane owns channels [(hg*8+h3)*32 + d3*4, +4)
__global__ __launch_bounds__(256) void k_attn(const short* __restrict__ qkvb,
                                              const float* __restrict__ rpb,
                                              short* __restrict__ outb) {
    __shared__ float lsh[4][8][50];
    // bijective XCD-chunk swizzle: 1568 blocks = 8 * 196
    const int xcd = blockIdx.x & 7, bidx = blockIdx.x >> 3;
    const int eff = xcd * 196 + bidx;
    const int wid = threadIdx.x >> 6, lane = threadIdx.x & 63;
    const int pix = eff * 2 + (wid >> 1);
    const int hg  = wid & 1;
    const int h3 = lane >> 3, d3 = lane & 7;
    const int h = hg * 8 + h3;
    const unsigned upix = (unsigned)pix;
    const int j = upix % 28u;
    const unsigned t2 = upix / 28u;
    const int i = t2 % 28u;
    const int b = t2 / 28u;
    const int si = min(max(i - 3, 0), 21), sj = min(max(j - 3, 0), 21);
    const int oi = si - i + 6, oj = sj - j + 6;
    const int pbase = b * HWPIX + si * 28 + sj;
    const int choff = h * 32 + d3 * 4;

    // q (4 bf16) -> f32, pre-scaled
    float q0, q1, q2, q3;
    {
        uint2 qu = *(const uint2*)(qkvb + (size_t)pix * 1536 + choff);
        const float sc = 0.17677669529663687f;
        q0 = __uint_as_float(qu.x << 16) * sc;
        q1 = __uint_as_float(qu.x & 0xffff0000u) * sc;
        q2 = __uint_as_float(qu.y << 16) * sc;
        q3 = __uint_as_float(qu.y & 0xffff0000u) * sc;
    }
    const short* kbase = qkvb + (size_t)pbase * 1536 + 512 + choff;
    const float* rb = rpb + h * 169 + oi * 13 + oj;

    // pass 1: logits
    for (int kr = 0; kr < 7; ++kr) {
        const short* krow = kbase + kr * (28 * 1536);
        const float* brow = rb + kr * 13;
#pragma unroll
        for (int kc = 0; kc < 7; ++kc) {
            uint2 ku = *(const uint2*)(krow + kc * 1536);
            float dot = q0 * __uint_as_float(ku.x << 16);
            dot = fmaf(q1, __uint_as_float(ku.x & 0xffff0000u), dot);
            dot = fmaf(q2, __uint_as_float(ku.y << 16), dot);
            dot = fmaf(q3, __uint_as_float(ku.y & 0xffff0000u), dot);
            dot += __shfl_xor(dot, 1);
            dot += __shfl_xor(dot, 2);
            dot += __shfl_xor(dot, 4);
            if (d3 == 0) lsh[wid][h3][kr * 7 + kc] = dot + brow[kc];
        }
    }
    __syncthreads();

    // pass 2: softmax (lane owns n = d3, d3+8, ...)
    float mx = -1e30f;
    for (int n = d3; n < 49; n += 8) mx = fmaxf(mx, lsh[wid][h3][n]);
    mx = fmaxf(mx, __shfl_xor(mx, 1));
    mx = fmaxf(mx, __shfl_xor(mx, 2));
    mx = fmaxf(mx, __shfl_xor(mx, 4));
    float s = 0.f;
    for (int n = d3; n < 49; n += 8) {
        float e = __expf(lsh[wid][h3][n] - mx);
        lsh[wid][h3][n] = e;
        s += e;
    }
    s += __shfl_xor(s, 1);
    s += __shfl_xor(s, 2);
    s += __shfl_xor(s, 4);
    __syncthreads();

    // pass 3: PV
    const short* vbase = qkvb + (size_t)pbase * 1536 + 1024 + choff;
    float o0 = 0.f, o1 = 0.f, o2 = 0.f, o3 = 0.f;
    for (int kr = 0; kr < 7; ++kr) {
        const short* vrow = vbase + kr * (28 * 1536);
        const float* prow = &lsh[wid][h3][kr * 7];
#pragma unroll
        for (int kc = 0; kc < 7; ++kc) {
            uint2 vu = *(const uint2*)(vrow + kc * 1536);
            float e = prow[kc];
            o0 = fmaf(e, __uint_as_float(vu.x << 16), o0);
            o1 = fmaf(e, __uint_as_float(vu.x & 0xffff0000u), o1);
            o2 = fmaf(e, __uint_as_float(vu.y << 16), o2);
            o3 = fmaf(e, __uint_as_float(vu.y & 0xffff0000u), o3);
        }
    }
    const float rs = 1.f / s;
    unsigned p0 = (unsigned short)f2b(o0 * rs) | ((unsigned)(unsigned short)f2b(o1 * rs) << 16);
    unsigned p1 = (unsigned short)f2b(o2 * rs) | ((unsigned)(unsigned short)f2b(o3 * rs) << 16);
    *(uint2*)&outb[(size_t)pix * 512 + choff] = make_uint2(p0, p1);
}

// ---------------- batchnorm finalize from 50 partials ----------------
__global__ __launch_bounds__(512) void k_bn_stats2(const float* __restrict__ part,
                                                   const float* __restrict__ g,
                                                   const float* __restrict__ be,
                                                   float* __restrict__ ss) {
    int c = threadIdx.x;
    float s = 0.f, s2 = 0.f;
    for (int p = 0; p < 50; ++p) {
        s  += part[p * CCH + c];
        s2 += part[50 * CCH + p * CCH + c];
    }
    float mean = s * (1.0f / NPIX);
    float var  = s2 * (1.0f / NPIX) - mean * mean;
    float rstd = rsqrtf(var + EPS);
    float scale = rstd * g[c];
    ss[c]       = scale;
    ss[CCH + c] = be[c] - mean * scale;
}

__global__ __launch_bounds__(256) void k_bn_apply(const float* __restrict__ y,
                                                  const float* __restrict__ ss,
                                                  float* __restrict__ x1,
                                                  short* __restrict__ x1b) {
    size_t idx = ((size_t)blockIdx.x * 256 + threadIdx.x) * 4;
    int c = (int)(idx & (CCH - 1));
    float4 v  = *(const float4*)&y[idx];
    float4 sc = *(const float4*)&ss[c];
    float4 sh = *(const float4*)&ss[CCH + c];
    v.x = fmaf(v.x, sc.x, sh.x); v.y = fmaf(v.y, sc.y, sh.y);
    v.z = fmaf(v.z, sc.z, sh.z); v.w = fmaf(v.w, sc.w, sh.w);
    *(float4*)&x1[idx] = v;
    unsigned a = (unsigned short)f2b(v.x) | ((unsigned)(unsigned short)f2b(v.y) << 16);
    unsigned b = (unsigned short)f2b(v.z) | ((unsigned)(unsigned short)f2b(v.w) << 16);
    *(uint2*)&x1b[idx] = make_uint2(a, b);
}

__global__ __launch_bounds__(256) void k_bn2_out(const float* __restrict__ y,
                                                 const float* __restrict__ ss,
                                                 float* __restrict__ out) {
    __shared__ float tile[32][33];
    int b  = blockIdx.z;
    int p0 = blockIdx.y * 32;
    int c0 = blockIdx.x * 32;
    int tx = threadIdx.x, ty = threadIdx.y;
    for (int i = ty; i < 32; i += 8) {
        int p = p0 + i, c = c0 + tx;
        float v = 0.f;
        if (p < HWPIX) v = fmaf(y[((size_t)b * HWPIX + p) * CCH + c], ss[c], ss[CCH + c]);
        tile[i][tx] = v;
    }
    __syncthreads();
    for (int i = ty; i < 32; i += 8) {
        int c = c0 + i, p = p0 + tx;
        if (p < HWPIX) out[((size_t)b * CCH + c) * HWPIX + p] = tile[tx][i];
    }
}

// ---------------- host launch ----------------
extern "C" void kernel_launch(void* const* d_in, const int* in_sizes, int n_in,
                              void* d_out, int out_size, void* d_ws, size_t ws_size,
                              hipStream_t stream) {
    const float* x      = (const float*)d_in[0];
    const float* qkv_w  = (const float*)d_in[1];
    const float* qkv_b  = (const float*)d_in[2];
    const float* proj_w = (const float*)d_in[3];
    const float* proj_b = (const float*)d_in[4];
    const float* rpb    = (const float*)d_in[5];
    const float* w1     = (const float*)d_in[6];
    const float* b1     = (const float*)d_in[7];
    const float* w2     = (const float*)d_in[8];
    const float* b2     = (const float*)d_in[9];
    const float* g1     = (const float*)d_in[10];
    const float* be1    = (const float*)d_in[11];
    const float* g2     = (const float*)d_in[12];
    const float* be2    = (const float*)d_in[13];
    float* out = (float*)d_out;

    float* ws    = (float*)d_ws;
    float* XH    = ws;                          // MPADx512 f32 (becomes X1)
    short* XHb   = (short*)(ws + 1638400);      // MPADx512 bf16 (becomes X1b)
    short* QKVb  = (short*)(ws + 2457600);      // MPADx1536 bf16 (becomes Tb)
    short* Tb    = QKVb;
    short* ATTb  = (short*)(ws + 4915200);      // MPADx512 bf16
    float* Y1    = ws + 5734400;                // MPADx512 f32 (becomes Y2)
    float* Y2    = Y1;
    short* Wb    = (short*)(ws + 7372800);      // 2097152 bf16
    short* Wqkv  = Wb;
    short* Wproj = Wb + 786432;
    short* W1b   = Wb + 1048576;
    short* W2b   = Wb + 1572864;
    float* PART  = ws + 8421376;                // 2*50*512
    float* SS    = ws + 8472576;                // 1024

    k_f2b_all<<<2048, 256, 0, stream>>>(qkv_w, proj_w, w1, w2, Wb);
    k_transpose_xh<<<dim3(25, 16, BATCH), dim3(32, 8), 0, stream>>>(x, XH, XHb);
    k_gemm_mfma<64, 128, 1536, 512, 0, 0, 1, 0>
        <<<dim3(50, 12), 256, 0, stream>>>(XHb, Wqkv, qkv_b, nullptr, nullptr, QKVb, nullptr);
    k_attn<<<1568, 256, 0, stream>>>(QKVb, rpb, ATTb);
    k_gemm_mfma<64, 128, 512, 512, 2, 1, 0, 1>
        <<<dim3(50, 4), 256, 0, stream>>>(ATTb, Wproj, proj_b, XH, Y1, nullptr, PART);
    k_bn_stats2<<<1, 512, 0, stream>>>(PART, g1, be1, SS);
    k_bn_apply<<<1568, 256, 0, stream>>>(Y1, SS, XH, XHb);
    k_gemm_mfma<64, 128, 1024, 512, 1, 0, 1, 0>
        <<<dim3(50, 8), 256, 0, stream>>>(XHb, W1b, b1, nullptr, nullptr, Tb, nullptr);
    k_gemm_mfma<64, 128, 512, 1024, 2, 1, 0, 1>
        <<<dim3(50, 4), 256, 0, stream>>>(Tb, W2b, b2, XH, Y2, nullptr, PART);
    k_bn_stats2<<<1, 512, 0, stream>>>(PART, g2, be2, SS);
    k_bn2_out<<<dim3(16, 25, BATCH), dim3(32, 8), 0, stream>>>(Y2, SS, out);
}

// Round 5
// 116.030 us; speedup vs baseline: 3.3943x; 1.1459x over previous
//
#include <hip/hip_runtime.h>
#include <hip/hip_bf16.h>
#include <math.h>

#define BATCH 4
#define CCH   512
#define HWPIX 784
#define NPIX  3136
#define MPAD  3200
#define EPS   1e-5f

using f32x4  = __attribute__((ext_vector_type(4))) float;
using bf16x8 = __attribute__((ext_vector_type(8))) __bf16;

__device__ __forceinline__ short f2b(float f) {
    unsigned u = __float_as_uint(f);
    unsigned r = (u + 0x7FFFu + ((u >> 16) & 1u)) >> 16;   // RNE
    return (short)r;
}
__device__ __forceinline__ unsigned pk2(float a, float b) {
    return (unsigned)(unsigned short)f2b(a) | ((unsigned)(unsigned short)f2b(b) << 16);
}

__device__ __forceinline__ void gload_lds16(const void* g, void* l) {
    __builtin_amdgcn_global_load_lds((const __attribute__((address_space(1))) void*)g,
                                     (__attribute__((address_space(3))) void*)l, 16, 0, 0);
}

// ---------------- prep: weights fp32->bf16 (qkv, proj, w2) + x transpose -> bf16 ----
__global__ __launch_bounds__(256) void k_prep(const float* __restrict__ qkv_w,
                                              const float* __restrict__ proj_w,
                                              const float* __restrict__ w2,
                                              const float* __restrict__ x,
                                              short* __restrict__ Wb,
                                              short* __restrict__ xhb) {
    __shared__ float tile[32][33];
    const int bid = blockIdx.x;
    if (bid < 1536) {
        int i = (bid * 256 + threadIdx.x) * 4;
        const float* src; int base;
        if (i < 786432)       { src = qkv_w;  base = 0; }
        else if (i < 1048576) { src = proj_w; base = 786432; }
        else                  { src = w2;     base = 1048576; }
        float4 v = *(const float4*)&src[i - base];
        *(uint2*)&Wb[i] = make_uint2(pk2(v.x, v.y), pk2(v.z, v.w));
        return;
    }
    const int t = bid - 1536;
    const int b = t / 400, r = t % 400;
    const int c0 = (r / 25) * 32, p0 = (r % 25) * 32;
    const int tx = threadIdx.x & 31, ty = threadIdx.x >> 5;
    for (int i = ty; i < 32; i += 8) {
        int c = c0 + i, p = p0 + tx;
        tile[i][tx] = (p < HWPIX) ? x[((size_t)b * CCH + c) * HWPIX + p] : 0.f;
    }
    __syncthreads();
    for (int i = ty; i < 32; i += 8) {
        int p = p0 + i, c = c0 + tx;
        if (p < HWPIX) xhb[((size_t)b * HWPIX + p) * CCH + c] = f2b(tile[tx][i]);
    }
}

// ---------------- bf16 MFMA GEMM ----------------
// EPI: 0=bias, 1=+gelu, 2=+residual from x (BCHW, guarded), 3=+BN1(Y1) on the fly
template<int BM, int BN, int N, int K, int EPI, int OUTF, int OUTB, int STATS>
__global__ __launch_bounds__(256) void k_gemm_mfma(
        const short* __restrict__ A, const short* __restrict__ Bw,
        const float* __restrict__ bias, const float* __restrict__ resx,
        const float* __restrict__ ss,
        float* __restrict__ Cf, short* __restrict__ Cb,
        float* __restrict__ part) {
    constexpr int BK = 64;
    constexpr int MR = BM / 32, NR = BN / 32;
    constexpr int AISS = BM / 32, BISS = BN / 32;
    __shared__ __align__(16) short As[BM * BK];
    __shared__ __align__(16) short Bs[BN * BK];
    const int tid  = threadIdx.x;
    const int wid  = tid >> 6, lane = tid & 63;
    const int wr   = wid >> 1, wc = wid & 1;
    const int m0   = blockIdx.x * BM, n0 = blockIdx.y * BN;
    const int srow = tid >> 3, skc = tid & 7;
    const int frow = lane & 15, fk = (lane >> 4) * 8;

    f32x4 acc[MR][NR];
    const f32x4 vzero = {0.f, 0.f, 0.f, 0.f};
#pragma unroll
    for (int m = 0; m < MR; ++m)
#pragma unroll
        for (int n = 0; n < NR; ++n) acc[m][n] = vzero;

    const short* Ab = A  + (size_t)(m0 + srow) * K + skc * 8;
    const short* Bb = Bw + (size_t)(n0 + srow) * K + skc * 8;

    for (int k0 = 0; k0 < K; k0 += BK) {
#pragma unroll
        for (int it = 0; it < AISS; ++it)
            gload_lds16(Ab + (size_t)it * 32 * K + k0, &As[(it * 256 + wid * 64) * 8]);
#pragma unroll
        for (int it = 0; it < BISS; ++it)
            gload_lds16(Bb + (size_t)it * 32 * K + k0, &Bs[(it * 256 + wid * 64) * 8]);
        __syncthreads();
#pragma unroll
        for (int kk = 0; kk < 2; ++kk) {
            bf16x8 af[MR], bfr[NR];
#pragma unroll
            for (int m = 0; m < MR; ++m)
                af[m] = *(const bf16x8*)&As[(wr * (BM / 2) + m * 16 + frow) * BK + kk * 32 + fk];
#pragma unroll
            for (int n = 0; n < NR; ++n)
                bfr[n] = *(const bf16x8*)&Bs[(wc * (BN / 2) + n * 16 + frow) * BK + kk * 32 + fk];
#pragma unroll
            for (int m = 0; m < MR; ++m)
#pragma unroll
                for (int n = 0; n < NR; ++n)
                    acc[m][n] = __builtin_amdgcn_mfma_f32_16x16x32_bf16(af[m], bfr[n], acc[m][n], 0, 0, 0);
        }
        __syncthreads();
    }
    const int crow0 = m0 + wr * (BM / 2) + (lane >> 4) * 4;
    const int ccol0 = n0 + wc * (BN / 2) + (lane & 15);
    float ls[NR], ls2[NR];
#pragma unroll
    for (int n = 0; n < NR; ++n) { ls[n] = 0.f; ls2[n] = 0.f; }
#pragma unroll
    for (int m = 0; m < MR; ++m) {
        const int row0 = crow0 + m * 16;              // 4-row group, 4-aligned
        const bool rv = row0 < NPIX;
        int bb = 0, hw = 0;
        if (EPI == 2) { bb = row0 / HWPIX; hw = row0 % HWPIX; }
#pragma unroll
        for (int n = 0; n < NR; ++n) {
            const int col = ccol0 + n * 16;
            const float bv = bias[col];
            float4 rx = make_float4(0.f, 0.f, 0.f, 0.f);
            if (EPI == 2 && rv)
                rx = *(const float4*)&resx[((size_t)bb * CCH + col) * HWPIX + hw];
#pragma unroll
            for (int j = 0; j < 4; ++j) {
                const int row = row0 + j;
                float v = acc[m][n][j] + bv;
                if (EPI == 1) v = 0.5f * v * (1.0f + erff(v * 0.70710678118654752f));
                if (EPI == 2) v += (&rx.x)[j];
                if (EPI == 3) v += fmaf(resx[(size_t)row * N + col], ss[col], ss[CCH + col]);
                if (OUTF) Cf[(size_t)row * N + col] = v;
                if (OUTB) Cb[(size_t)row * N + col] = f2b(v);
                if (STATS && row < NPIX) { ls[n] += v; ls2[n] = fmaf(v, v, ls2[n]); }
            }
        }
    }
    if (STATS) {
        float* red  = (float*)As;            // [8][BN]
        float* red2 = red + 8 * BN;
        const int rrow = wr * 4 + (lane >> 4);
#pragma unroll
        for (int n = 0; n < NR; ++n) {
            int cslot = wc * (BN / 2) + n * 16 + (lane & 15);
            red [rrow * BN + cslot] = ls[n];
            red2[rrow * BN + cslot] = ls2[n];
        }
        __syncthreads();
        if (tid < BN) {
            float s = 0.f, s2 = 0.f;
#pragma unroll
            for (int r = 0; r < 8; ++r) { s += red[r * BN + tid]; s2 += red2[r * BN + tid]; }
            part[blockIdx.x * N + n0 + tid]          = s;
            part[50 * N + blockIdx.x * N + n0 + tid] = s2;
        }
    }
}

// ---------------- neighborhood attention: wave per (pixel, 8-head group) ----------
__global__ __launch_bounds__(256) void k_attn(const short* __restrict__ qkvb,
                                              const float* __restrict__ rpb,
                                              short* __restrict__ outb) {
    __shared__ float lsh[4][8][50];
    const int xcd = blockIdx.x & 7, bidx = blockIdx.x >> 3;
    const int eff = xcd * 196 + bidx;
    const int wid = threadIdx.x >> 6, lane = threadIdx.x & 63;
    const int pix = eff * 2 + (wid >> 1);
    const int hg  = wid & 1;
    const int h3 = lane >> 3, d3 = lane & 7;
    const int h = hg * 8 + h3;
    const unsigned upix = (unsigned)pix;
    const int j = upix % 28u;
    const unsigned t2 = upix / 28u;
    const int i = t2 % 28u;
    const int b = t2 / 28u;
    const int si = min(max(i - 3, 0), 21), sj = min(max(j - 3, 0), 21);
    const int oi = si - i + 6, oj = sj - j + 6;
    const int pbase = b * HWPIX + si * 28 + sj;
    const int choff = h * 32 + d3 * 4;

    float q0, q1, q2, q3;
    {
        uint2 qu = *(const uint2*)(qkvb + (size_t)pix * 1536 + choff);
        const float sc = 0.17677669529663687f;
        q0 = __uint_as_float(qu.x << 16) * sc;
        q1 = __uint_as_float(qu.x & 0xffff0000u) * sc;
        q2 = __uint_as_float(qu.y << 16) * sc;
        q3 = __uint_as_float(qu.y & 0xffff0000u) * sc;
    }
    const short* kbase = qkvb + (size_t)pbase * 1536 + 512 + choff;
    const float* rb = rpb + h * 169 + oi * 13 + oj;

    for (int kr = 0; kr < 7; ++kr) {
        const short* krow = kbase + kr * (28 * 1536);
        const float* brow = rb + kr * 13;
#pragma unroll
        for (int kc = 0; kc < 7; ++kc) {
            uint2 ku = *(const uint2*)(krow + kc * 1536);
            float dot = q0 * __uint_as_float(ku.x << 16);
            dot = fmaf(q1, __uint_as_float(ku.x & 0xffff0000u), dot);
            dot = fmaf(q2, __uint_as_float(ku.y << 16), dot);
            dot = fmaf(q3, __uint_as_float(ku.y & 0xffff0000u), dot);
            dot += __shfl_xor(dot, 1);
            dot += __shfl_xor(dot, 2);
            dot += __shfl_xor(dot, 4);
            if (d3 == 0) lsh[wid][h3][kr * 7 + kc] = dot + brow[kc];
        }
    }
    __syncthreads();

    float mx = -1e30f;
    for (int n = d3; n < 49; n += 8) mx = fmaxf(mx, lsh[wid][h3][n]);
    mx = fmaxf(mx, __shfl_xor(mx, 1));
    mx = fmaxf(mx, __shfl_xor(mx, 2));
    mx = fmaxf(mx, __shfl_xor(mx, 4));
    float s = 0.f;
    for (int n = d3; n < 49; n += 8) {
        float e = __expf(lsh[wid][h3][n] - mx);
        lsh[wid][h3][n] = e;
        s += e;
    }
    s += __shfl_xor(s, 1);
    s += __shfl_xor(s, 2);
    s += __shfl_xor(s, 4);
    __syncthreads();

    const short* vbase = qkvb + (size_t)pbase * 1536 + 1024 + choff;
    float o0 = 0.f, o1 = 0.f, o2 = 0.f, o3 = 0.f;
    for (int kr = 0; kr < 7; ++kr) {
        const short* vrow = vbase + kr * (28 * 1536);
        const float* prow = &lsh[wid][h3][kr * 7];
#pragma unroll
        for (int kc = 0; kc < 7; ++kc) {
            uint2 vu = *(const uint2*)(vrow + kc * 1536);
            float e = prow[kc];
            o0 = fmaf(e, __uint_as_float(vu.x << 16), o0);
            o1 = fmaf(e, __uint_as_float(vu.x & 0xffff0000u), o1);
            o2 = fmaf(e, __uint_as_float(vu.y << 16), o2);
            o3 = fmaf(e, __uint_as_float(vu.y & 0xffff0000u), o3);
        }
    }
    const float rs = 1.f / s;
    *(uint2*)&outb[(size_t)pix * 512 + choff] =
        make_uint2(pk2(o0 * rs, o1 * rs), pk2(o2 * rs, o3 * rs));
}

// ---------------- batchnorm finalize from 50 partials ----------------
__global__ __launch_bounds__(512) void k_bn_stats2(const float* __restrict__ part,
                                                   const float* __restrict__ g,
                                                   const float* __restrict__ be,
                                                   float* __restrict__ ss) {
    int c = threadIdx.x;
    float s = 0.f, s2 = 0.f;
    for (int p = 0; p < 50; ++p) {
        s  += part[p * CCH + c];
        s2 += part[50 * CCH + p * CCH + c];
    }
    float mean = s * (1.0f / NPIX);
    float var  = s2 * (1.0f / NPIX) - mean * mean;
    float rstd = rsqrtf(var + EPS);
    float scale = rstd * g[c];
    ss[c]       = scale;
    ss[CCH + c] = be[c] - mean * scale;
}

// ---------------- fold BN1 into W1: w1s = bf16(sc*w1), b1c = b1 + sh.w1row ----------
__global__ __launch_bounds__(256) void k_fold_w1(const float* __restrict__ w1,
                                                 const float* __restrict__ b1,
                                                 const float* __restrict__ ss,
                                                 short* __restrict__ w1s,
                                                 float* __restrict__ b1c) {
    const int n = blockIdx.x * 4 + (threadIdx.x >> 6);
    const int lane = threadIdx.x & 63;
    const int c = lane * 8;
    const float* wr = w1 + (size_t)n * CCH + c;
    float4 wa = *(const float4*)wr, wb = *(const float4*)(wr + 4);
    float4 sa = *(const float4*)&ss[c], sb = *(const float4*)&ss[c + 4];
    float4 ha = *(const float4*)&ss[CCH + c], hb = *(const float4*)&ss[CCH + c + 4];
    uint4 o;
    o.x = pk2(wa.x * sa.x, wa.y * sa.y);
    o.y = pk2(wa.z * sa.z, wa.w * sa.w);
    o.z = pk2(wb.x * sb.x, wb.y * sb.y);
    o.w = pk2(wb.z * sb.z, wb.w * sb.w);
    *(uint4*)&w1s[(size_t)n * CCH + c] = o;
    float p = wa.x * ha.x + wa.y * ha.y + wa.z * ha.z + wa.w * ha.w
            + wb.x * hb.x + wb.y * hb.y + wb.z * hb.z + wb.w * hb.w;
#pragma unroll
    for (int off = 32; off >= 1; off >>= 1) p += __shfl_xor(p, off);
    if (lane == 0) b1c[n] = b1[n] + p;
}

// ---------------- BN2 apply + transpose to BCHW output ----------------
__global__ __launch_bounds__(256) void k_bn2_out(const float* __restrict__ y,
                                                 const float* __restrict__ ss,
                                                 float* __restrict__ out) {
    __shared__ float tile[32][33];
    int b  = blockIdx.z;
    int p0 = blockIdx.y * 32;
    int c0 = blockIdx.x * 32;
    int tx = threadIdx.x, ty = threadIdx.y;
    for (int i = ty; i < 32; i += 8) {
        int p = p0 + i, c = c0 + tx;
        float v = 0.f;
        if (p < HWPIX) v = fmaf(y[((size_t)b * HWPIX + p) * CCH + c], ss[c], ss[CCH + c]);
        tile[i][tx] = v;
    }
    __syncthreads();
    for (int i = ty; i < 32; i += 8) {
        int c = c0 + i, p = p0 + tx;
        if (p < HWPIX) out[((size_t)b * CCH + c) * HWPIX + p] = tile[tx][i];
    }
}

// ---------------- host launch ----------------
extern "C" void kernel_launch(void* const* d_in, const int* in_sizes, int n_in,
                              void* d_out, int out_size, void* d_ws, size_t ws_size,
                              hipStream_t stream) {
    const float* x      = (const float*)d_in[0];
    const float* qkv_w  = (const float*)d_in[1];
    const float* qkv_b  = (const float*)d_in[2];
    const float* proj_w = (const float*)d_in[3];
    const float* proj_b = (const float*)d_in[4];
    const float* rpb    = (const float*)d_in[5];
    const float* w1     = (const float*)d_in[6];
    const float* b1     = (const float*)d_in[7];
    const float* w2     = (const float*)d_in[8];
    const float* b2     = (const float*)d_in[9];
    const float* g1     = (const float*)d_in[10];
    const float* be1    = (const float*)d_in[11];
    const float* g2     = (const float*)d_in[12];
    const float* be2    = (const float*)d_in[13];
    float* out = (float*)d_out;

    float* ws    = (float*)d_ws;
    float* Y1    = ws;                          // MPADx512 f32
    float* Y2    = ws + 1638400;                // MPADx512 f32
    short* XHb   = (short*)(ws + 3276800);      // MPADx512 bf16
    short* QKVb  = (short*)(ws + 4096000);      // MPADx1536 bf16 (becomes Tb)
    short* Tb    = QKVb;
    short* ATTb  = (short*)(ws + 6553600);      // MPADx512 bf16
    short* Y1b   = (short*)(ws + 7372800);      // MPADx512 bf16
    short* Wb    = (short*)(ws + 8192000);
    short* Wqkv  = Wb;
    short* Wproj = Wb + 786432;
    short* W2b   = Wb + 1048576;
    short* W1s   = Wb + 1572864;                // 524288 bf16 (BN1-folded)
    float* PART  = ws + 9240576;                // 2*50*512
    float* SS1   = ws + 9291776;
    float* SS2   = ws + 9292800;
    float* B1c   = ws + 9293824;                // 1024 f32

    k_prep<<<3136, 256, 0, stream>>>(qkv_w, proj_w, w2, x, Wb, XHb);
    k_gemm_mfma<128, 128, 1536, 512, 0, 0, 1, 0>
        <<<dim3(25, 12), 256, 0, stream>>>(XHb, Wqkv, qkv_b, nullptr, nullptr,
                                           nullptr, QKVb, nullptr);
    k_attn<<<1568, 256, 0, stream>>>(QKVb, rpb, ATTb);
    k_gemm_mfma<64, 64, 512, 512, 2, 1, 1, 1>
        <<<dim3(50, 8), 256, 0, stream>>>(ATTb, Wproj, proj_b, x, nullptr,
                                          Y1, Y1b, PART);
    k_bn_stats2<<<1, 512, 0, stream>>>(PART, g1, be1, SS1);
    k_fold_w1<<<256, 256, 0, stream>>>(w1, b1, SS1, W1s, B1c);
    k_gemm_mfma<64, 128, 1024, 512, 1, 0, 1, 0>
        <<<dim3(50, 8), 256, 0, stream>>>(Y1b, W1s, B1c, nullptr, nullptr,
                                          nullptr, Tb, nullptr);
    k_gemm_mfma<64, 64, 512, 1024, 3, 1, 0, 1>
        <<<dim3(50, 8), 256, 0, stream>>>(Tb, W2b, b2, Y1, SS1,
                                          Y2, nullptr, PART);
    k_bn_stats2<<<1, 512, 0, stream>>>(PART, g2, be2, SS2);
    k_bn2_out<<<dim3(16, 25, BATCH), dim3(32, 8), 0, stream>>>(Y2, SS2, out);
}